// Round 12
// baseline (269.354 us; speedup 1.0000x reference)
//
#include <hip/hip_runtime.h>
#include <math.h>

#define NEG_SLOPE 0.2f
__device__ __forceinline__ float lrelu(float x){ return x >= 0.f ? x : NEG_SLOPE * x; }

typedef __attribute__((ext_vector_type(8))) short bf16x8;
typedef __attribute__((ext_vector_type(4))) float f32x4;

__device__ __forceinline__ float wred_sum(float v){
  #pragma unroll
  for (int o = 32; o; o >>= 1) v += __shfl_xor(v, o, 64);
  return v;
}

__device__ __forceinline__ float bfhi_f(float f){
  return __uint_as_float(__float_as_uint(f) & 0xFFFF0000u);
}
// fp32 -> bf16 RTNE
__device__ __forceinline__ unsigned short f2bf(float f){
  unsigned u = __float_as_uint(f);
  unsigned r = u + 0x7FFFu + ((u >> 16) & 1u);
  return (unsigned short)(r >> 16);
}

// ================= bucketed CSR build =================
__global__ __launch_bounds__(256) void k_bincnt(const int* __restrict__ ei, int E, int N, int nb,
                                                unsigned* __restrict__ bcnt){
  __shared__ unsigned h[512];
  const int tot = E + N;
  for (int i = threadIdx.x; i < nb; i += 256) h[i] = 0;
  __syncthreads();
  int base = blockIdx.x * 8192;
  #pragma unroll 4
  for (int j = 0; j < 32; j++){
    int e = base + threadIdx.x + j * 256;
    if (e < tot){
      unsigned d = (e < E) ? (unsigned)ei[E + e] : (unsigned)(e - E);
      atomicAdd(&h[d >> 8], 1u);
    }
  }
  __syncthreads();
  for (int i = threadIdx.x; i < nb; i += 256)
    if (h[i]) atomicAdd(&bcnt[i], h[i]);
}

__global__ void k_bscan(const unsigned* __restrict__ bcnt, unsigned* __restrict__ bbase,
                        unsigned* __restrict__ bcur, int nb, int tot){
  __shared__ unsigned s[512];
  int t = threadIdx.x;
  unsigned v = (t < nb) ? bcnt[t] : 0u;
  s[t] = v; __syncthreads();
  for (int off = 1; off < 512; off <<= 1){
    unsigned x = (t >= off) ? s[t - off] : 0u; __syncthreads();
    s[t] += x; __syncthreads();
  }
  if (t < nb){ unsigned b = s[t] - v; bbase[t] = b; bcur[t] = b; }
  if (t == 0) bbase[nb] = (unsigned)tot;
}

__global__ __launch_bounds__(256) void k_binscat(const int* __restrict__ ei, int E, int N, int nb,
    unsigned* __restrict__ bcur, unsigned* __restrict__ staged){
  __shared__ unsigned sd[8192];
  __shared__ unsigned hist[512];
  __shared__ unsigned runb[512];
  const int tot = E + N;
  for (int i = threadIdx.x; i < nb; i += 256) hist[i] = 0;
  __syncthreads();
  int base = blockIdx.x * 8192;
  #pragma unroll 4
  for (int j = 0; j < 32; j++){
    int idx = threadIdx.x + j * 256;
    int e = base + idx;
    unsigned d = 0xFFFFFFFFu;
    if (e < tot) d = (e < E) ? (unsigned)ei[E + e] : (unsigned)(e - E);
    sd[idx] = d;
    if (d != 0xFFFFFFFFu) atomicAdd(&hist[d >> 8], 1u);
  }
  __syncthreads();
  for (int i = threadIdx.x; i < nb; i += 256){
    unsigned c = hist[i];
    runb[i] = c ? atomicAdd(&bcur[i], c) : 0u;
    hist[i] = 0;
  }
  __syncthreads();
  #pragma unroll 4
  for (int j = 0; j < 32; j++){
    int idx = threadIdx.x + j * 256;
    unsigned d = sd[idx];
    if (d == 0xFFFFFFFFu) continue;
    int e = base + idx;
    unsigned s = (e < E) ? (unsigned)ei[e] : d;
    unsigned b = d >> 8;
    unsigned pos = runb[b] + atomicAdd(&hist[b], 1u);
    staged[pos] = s | ((d & 255u) << 20);
  }
}

__global__ __launch_bounds__(256) void k_csr(const unsigned* __restrict__ bbase,
    const unsigned* __restrict__ staged, int N,
    unsigned* __restrict__ off_, unsigned* __restrict__ cur, int* __restrict__ srcids){
  __shared__ unsigned cnt[256], scn[256], cnt2[256];
  int b = blockIdx.x, t = threadIdx.x;
  unsigned beg = bbase[b], end = bbase[b + 1];
  cnt[t] = 0; cnt2[t] = 0;
  __syncthreads();
  for (unsigned i = beg + t; i < end; i += 256)
    atomicAdd(&cnt[staged[i] >> 20], 1u);
  __syncthreads();
  unsigned v = cnt[t];
  scn[t] = v; __syncthreads();
  for (int off = 1; off < 256; off <<= 1){
    unsigned x = (t >= off) ? scn[t - off] : 0u; __syncthreads();
    scn[t] += x; __syncthreads();
  }
  unsigned ex = scn[t] - v;
  int d = b * 256 + t;
  if (d < N){ off_[d] = beg + ex; cur[d] = beg + ex + v; }
  cnt[t] = ex;
  __syncthreads();
  for (unsigned i = beg + t; i < end; i += 256){
    unsigned u = staged[i];
    unsigned dl = u >> 20;
    unsigned pos = beg + cnt[dl] + atomicAdd(&cnt2[dl], 1u);
    srcids[pos] = (int)(u & 0xFFFFFu);
  }
}

// ============ W1 prep: Wt_hi/Wt_lo[64][256] bf16 ============
__global__ void k_wprep(const float* __restrict__ W, short* __restrict__ wt_hi,
                        short* __restrict__ wt_lo){
  int i = blockIdx.x * 256 + threadIdx.x;    // 16384
  int k = i >> 6, c = i & 63;
  float v = W[i];
  unsigned u = __float_as_uint(v);
  wt_hi[c * 256 + k] = (short)(u >> 16);
  float lo = v - bfhi_f(v);
  wt_lo[c * 256 + k] = (short)(__float_as_uint(lo) >> 16);
}

// ============ W2 prep: [48][64] bf16 hi/lo (cols 40-47 zero) ============
__global__ void k_w2prep(const float* __restrict__ W2, short* __restrict__ hi,
                         short* __restrict__ lo){
  int i = blockIdx.x * 256 + threadIdx.x;    // 3072
  if (i >= 48 * 64) return;
  int c = i >> 6, k = i & 63;
  float v = (c < 40) ? W2[k * 40 + c] : 0.f;
  unsigned u = __float_as_uint(v);
  hi[c * 64 + k] = (short)(u >> 16);
  float l = v - bfhi_f(v);
  lo[c * 64 + k] = (short)(__float_as_uint(l) >> 16);
}

// ============ GEMM1 via MFMA: 16 loads up-front, VGPR budget widened to 128 ============
// __launch_bounds__(256, 4): 4 waves/SIMD min -> VGPR cap 128, so xv[16] (64 VGPRs)
// stays resident and all 16 loads issue back-to-back (MLP=16). Grid caps occupancy
// at ~24 waves/CU anyway, so the 8-waves/SIMD target the compiler was protecting
// (by capping VGPR at 64 and re-sinking the loads, R9/R11) was unreachable.
__global__ __launch_bounds__(256, 4) void k_gemm1_mfma(const float* __restrict__ x,
    const short* __restrict__ wt_hi, const short* __restrict__ wt_lo,
    const float* __restrict__ a1s, const float* __restrict__ a1d,
    unsigned short* __restrict__ h1b, float* __restrict__ as_, float* __restrict__ ad_, int N){
  int lane = threadIdx.x & 63;
  int wv   = threadIdx.x >> 6;
  int r0   = blockIdx.x * 64 + wv * 16;
  if (r0 >= N) return;
  int col16 = lane & 15;
  int kg    = lane >> 4;
  const float4* xr = (const float4*)(x + (size_t)min(r0 + col16, N - 1) * 256 + kg * 8);

  // issue the wave's full 256-B row fragment as 16 back-to-back loads
  float4 xv[16];
  #pragma unroll
  for (int kt = 0; kt < 8; kt++){
    xv[2 * kt]     = xr[kt * 8];
    xv[2 * kt + 1] = xr[kt * 8 + 1];
  }
  __builtin_amdgcn_sched_barrier(0);

  f32x4 acc[4];
  #pragma unroll
  for (int ct = 0; ct < 4; ct++) acc[ct] = (f32x4){0.f, 0.f, 0.f, 0.f};

  #pragma unroll
  for (int kt = 0; kt < 8; kt++){
    float4 v0 = xv[2 * kt], v1 = xv[2 * kt + 1];
    unsigned u[8] = {__float_as_uint(v0.x), __float_as_uint(v0.y), __float_as_uint(v0.z), __float_as_uint(v0.w),
                     __float_as_uint(v1.x), __float_as_uint(v1.y), __float_as_uint(v1.z), __float_as_uint(v1.w)};
    union { bf16x8 v; unsigned u[4]; } ahi, alo;
    #pragma unroll
    for (int j = 0; j < 4; j++)
      ahi.u[j] = __builtin_amdgcn_perm(u[2*j+1], u[2*j], 0x07060302);
    float lo[8];
    lo[0] = v0.x - bfhi_f(v0.x); lo[1] = v0.y - bfhi_f(v0.y);
    lo[2] = v0.z - bfhi_f(v0.z); lo[3] = v0.w - bfhi_f(v0.w);
    lo[4] = v1.x - bfhi_f(v1.x); lo[5] = v1.y - bfhi_f(v1.y);
    lo[6] = v1.z - bfhi_f(v1.z); lo[7] = v1.w - bfhi_f(v1.w);
    #pragma unroll
    for (int j = 0; j < 4; j++)
      alo.u[j] = __builtin_amdgcn_perm(__float_as_uint(lo[2*j+1]), __float_as_uint(lo[2*j]), 0x07060302);

    #pragma unroll
    for (int ct = 0; ct < 4; ct++){
      int wcol = ct * 16 + col16;
      const bf16x8 bhi = *(const bf16x8*)(wt_hi + wcol * 256 + kt * 32 + kg * 8);
      const bf16x8 blo = *(const bf16x8*)(wt_lo + wcol * 256 + kt * 32 + kg * 8);
      acc[ct] = __builtin_amdgcn_mfma_f32_16x16x32_bf16(ahi.v, bhi, acc[ct], 0, 0, 0);
      acc[ct] = __builtin_amdgcn_mfma_f32_16x16x32_bf16(ahi.v, blo, acc[ct], 0, 0, 0);
      acc[ct] = __builtin_amdgcn_mfma_f32_16x16x32_bf16(alo.v, bhi, acc[ct], 0, 0, 0);
    }
  }

  float cs[4], cd[4];
  #pragma unroll
  for (int ct = 0; ct < 4; ct++){ cs[ct] = a1s[ct * 16 + col16]; cd[ct] = a1d[ct * 16 + col16]; }
  #pragma unroll
  for (int r = 0; r < 4; r++){
    int rr = r0 + kg * 4 + r;
    bool ok = rr < N;
    #pragma unroll
    for (int ct = 0; ct < 4; ct++){
      float v = acc[ct][r];
      if (ok) h1b[(size_t)rr * 64 + ct * 16 + col16] = f2bf(v);
      float s = v * cs[ct];
      float t = v * cd[ct];
      s += __shfl_xor(s, 1, 64); s += __shfl_xor(s, 2, 64); s += __shfl_xor(s, 4, 64);
      t += __shfl_xor(t, 1, 64); t += __shfl_xor(t, 2, 64); t += __shfl_xor(t, 4, 64);
      if (ok && (col16 & 7) == 0){
        int head = ct * 2 + (col16 >> 3);
        as_[(size_t)rr * 8 + head] = s;
        ad_[(size_t)rr * 8 + head] = t;
      }
    }
  }
}

// ============ layer-1 per-dst gather: staged srcids, MLP-4 channel phase ============
__global__ __launch_bounds__(256) void k_gat1(const unsigned* __restrict__ off_, const unsigned* __restrict__ cur,
    const int* __restrict__ srcids, const float* __restrict__ as_, const float* __restrict__ ad_,
    const unsigned short* __restrict__ h1b, const float* __restrict__ b1,
    unsigned short* __restrict__ out1b, int N){
  int lane = threadIdx.x & 63;
  int wv   = threadIdx.x >> 6;
  int d    = blockIdx.x * 4 + wv;
  if (d >= N) return;
  __shared__ float lds_p[4][64 * 8];
  __shared__ int   lds_s[4][64];
  float* lp = lds_p[wv];
  int*   ls = lds_s[wv];
  unsigned beg = off_[d], fin = cur[d];

  int e8 = lane >> 3, h = lane & 7;                  // exp-phase layout
  int c0 = lane & 31, pe = lane >> 5, hh = c0 >> 2;  // channel-phase layout
  float adh = ad_[(size_t)d * 8 + h];
  float psacc = 0.f, accx = 0.f, accy = 0.f;

  for (unsigned base = beg; base < fin; base += 64){
    int nthis = (int)min(64u, fin - base);
    unsigned i = base + lane;
    ls[lane] = (i < fin) ? srcids[i] : 0;            // one coalesced stage
    asm volatile("s_waitcnt lgkmcnt(0)" ::: "memory");
    __builtin_amdgcn_sched_barrier(0);
    for (int j = 0; j < nthis; j += 8){
      int eloc = j + e8;
      int s = ls[eloc];
      float p = 0.f;
      if (eloc < nthis) p = __expf(lrelu(as_[(size_t)s * 8 + h] + adh));
      lp[eloc * 8 + h] = p;
      psacc += p;
    }
    asm volatile("s_waitcnt lgkmcnt(0)" ::: "memory");
    __builtin_amdgcn_sched_barrier(0);
    for (int e = 0; e < nthis; e += 8){
      int e0 = e + pe, e1 = e + 2 + pe, e2 = e + 4 + pe, e3 = e + 6 + pe;
      float p0 = lp[e0 * 8 + hh], p1 = lp[e1 * 8 + hh];
      float p2 = lp[e2 * 8 + hh], p3 = lp[e3 * 8 + hh];
      int s0 = ls[e0], s1 = ls[e1], s2 = ls[e2], s3 = ls[e3];
      unsigned u0 = *(const unsigned*)(h1b + (size_t)s0 * 64 + c0 * 2);
      unsigned u1 = *(const unsigned*)(h1b + (size_t)s1 * 64 + c0 * 2);
      unsigned u2 = *(const unsigned*)(h1b + (size_t)s2 * 64 + c0 * 2);
      unsigned u3 = *(const unsigned*)(h1b + (size_t)s3 * 64 + c0 * 2);
      accx = fmaf(p0, __uint_as_float(u0 << 16), accx);
      accy = fmaf(p0, __uint_as_float(u0 & 0xFFFF0000u), accy);
      accx = fmaf(p1, __uint_as_float(u1 << 16), accx);
      accy = fmaf(p1, __uint_as_float(u1 & 0xFFFF0000u), accy);
      accx = fmaf(p2, __uint_as_float(u2 << 16), accx);
      accy = fmaf(p2, __uint_as_float(u2 & 0xFFFF0000u), accy);
      accx = fmaf(p3, __uint_as_float(u3 << 16), accx);
      accy = fmaf(p3, __uint_as_float(u3 & 0xFFFF0000u), accy);
    }
    asm volatile("" ::: "memory");
  }
  float den = psacc;
  den += __shfl_xor(den, 8, 64);
  den += __shfl_xor(den, 16, 64);
  den += __shfl_xor(den, 32, 64);
  float mydenv = __shfl(den, hh, 64);
  accx += __shfl_xor(accx, 32, 64);
  accy += __shfl_xor(accy, 32, 64);
  if (lane < 32){
    int ch = lane * 2;
    float v0 = accx / mydenv + b1[ch];
    float v1 = accy / mydenv + b1[ch + 1];
    ushort2 o;
    o.x = f2bf(v0 > 0.f ? v0 : 0.f);
    o.y = f2bf(v1 > 0.f ? v1 : 0.f);
    *(ushort2*)(out1b + (size_t)d * 64 + ch) = o;
  }
}

// ============ GEMM2 via MFMA (bf16 A, hi/lo B) + fused alpha2 ============
__global__ __launch_bounds__(256) void k_gemm2m(const unsigned short* __restrict__ out1b,
    const short* __restrict__ wt2_hi, const short* __restrict__ wt2_lo,
    const float* __restrict__ a2s, const float* __restrict__ a2d,
    unsigned short* __restrict__ h2b, float* __restrict__ as_, float* __restrict__ ad_, int N){
  int lane = threadIdx.x & 63;
  int wv   = threadIdx.x >> 6;
  int r0   = blockIdx.x * 64 + wv * 16;
  if (r0 >= N) return;
  int col16 = lane & 15;
  int kg    = lane >> 4;
  const unsigned short* ar = out1b + (size_t)min(r0 + col16, N - 1) * 64 + kg * 8;

  f32x4 acc[3];
  #pragma unroll
  for (int ct = 0; ct < 3; ct++) acc[ct] = (f32x4){0.f, 0.f, 0.f, 0.f};

  #pragma unroll
  for (int kt = 0; kt < 2; kt++){
    const bf16x8 a = *(const bf16x8*)(ar + kt * 32);
    #pragma unroll
    for (int ct = 0; ct < 3; ct++){
      int wcol = ct * 16 + col16;
      const bf16x8 bhi = *(const bf16x8*)(wt2_hi + wcol * 64 + kt * 32 + kg * 8);
      const bf16x8 blo = *(const bf16x8*)(wt2_lo + wcol * 64 + kt * 32 + kg * 8);
      acc[ct] = __builtin_amdgcn_mfma_f32_16x16x32_bf16(a, bhi, acc[ct], 0, 0, 0);
      acc[ct] = __builtin_amdgcn_mfma_f32_16x16x32_bf16(a, blo, acc[ct], 0, 0, 0);
    }
  }

  float cs[3], cd[3];
  #pragma unroll
  for (int ct = 0; ct < 3; ct++){
    int col = ct * 16 + col16;
    bool okc = col < 40;
    cs[ct] = okc ? a2s[col] : 0.f;
    cd[ct] = okc ? a2d[col] : 0.f;
  }
  #pragma unroll
  for (int r = 0; r < 4; r++){
    int rr = r0 + kg * 4 + r;
    bool ok = rr < N;
    float s = 0.f, t = 0.f;
    #pragma unroll
    for (int ct = 0; ct < 3; ct++){
      s = fmaf(acc[ct][r], cs[ct], s);
      t = fmaf(acc[ct][r], cd[ct], t);
      int col = ct * 16 + col16;
      if (ok && col < 40) h2b[(size_t)rr * 40 + col] = f2bf(acc[ct][r]);
    }
    s += __shfl_xor(s, 1, 64); s += __shfl_xor(s, 2, 64);
    s += __shfl_xor(s, 4, 64); s += __shfl_xor(s, 8, 64);
    t += __shfl_xor(t, 1, 64); t += __shfl_xor(t, 2, 64);
    t += __shfl_xor(t, 4, 64); t += __shfl_xor(t, 8, 64);
    if (ok && col16 == 0){ as_[rr] = s; ad_[rr] = t; }
  }
}

// ============ layer-2 per-dst gather (H=1, C=40), MLP-4 + fused bias+log_softmax ============
__global__ __launch_bounds__(256) void k_gat2(const unsigned* __restrict__ off_, const unsigned* __restrict__ cur,
    const int* __restrict__ srcids, const float* __restrict__ as_, const float* __restrict__ ad_,
    const unsigned short* __restrict__ h2b, const float* __restrict__ b2, float* __restrict__ out, int N){
  int lane = threadIdx.x & 63;
  int wv   = threadIdx.x >> 6;
  int d    = blockIdx.x * 4 + wv;
  if (d >= N) return;
  __shared__ float lds_p[4][64];
  __shared__ int   lds_s[4][64];
  float* lp = lds_p[wv];
  int*   ls = lds_s[wv];
  unsigned beg = off_[d], fin = cur[d];
  float add = ad_[d];

  int c0 = lane & 31;
  int pe = lane >> 5;
  int idx = c0 < 20 ? c0 : 19;
  float ps = 0.f, accx = 0.f, accy = 0.f;

  for (unsigned base = beg; base < fin; base += 64){
    unsigned i = base + lane;
    int nthis = (int)min(64u, fin - base);
    if (i < fin){
      int s = srcids[i];
      float p = __expf(lrelu(as_[s] + add));
      ps += p; ls[lane] = s; lp[lane] = p;
    } else { ls[lane] = 0; lp[lane] = 0.f; }
    asm volatile("s_waitcnt lgkmcnt(0)" ::: "memory");
    __builtin_amdgcn_sched_barrier(0);
    for (int e = 0; e < nthis; e += 8){
      int e0 = e + pe, e1 = e + 2 + pe, e2 = e + 4 + pe, e3 = e + 6 + pe;
      float p0 = lp[e0], p1 = lp[e1], p2 = lp[e2], p3 = lp[e3];
      int s0 = ls[e0], s1 = ls[e1], s2 = ls[e2], s3 = ls[e3];
      unsigned u0 = *(const unsigned*)(h2b + (size_t)s0 * 40 + idx * 2);
      unsigned u1 = *(const unsigned*)(h2b + (size_t)s1 * 40 + idx * 2);
      unsigned u2 = *(const unsigned*)(h2b + (size_t)s2 * 40 + idx * 2);
      unsigned u3 = *(const unsigned*)(h2b + (size_t)s3 * 40 + idx * 2);
      accx = fmaf(p0, __uint_as_float(u0 << 16), accx);
      accy = fmaf(p0, __uint_as_float(u0 & 0xFFFF0000u), accy);
      accx = fmaf(p1, __uint_as_float(u1 << 16), accx);
      accy = fmaf(p1, __uint_as_float(u1 & 0xFFFF0000u), accy);
      accx = fmaf(p2, __uint_as_float(u2 << 16), accx);
      accy = fmaf(p2, __uint_as_float(u2 & 0xFFFF0000u), accy);
      accx = fmaf(p3, __uint_as_float(u3 << 16), accx);
      accy = fmaf(p3, __uint_as_float(u3 & 0xFFFF0000u), accy);
    }
    asm volatile("" ::: "memory");
  }
  ps = wred_sum(ps);
  accx += __shfl_xor(accx, 32, 64);
  accy += __shfl_xor(accy, 32, 64);

  float v0 = accx / ps + b2[idx * 2];
  float v1 = accy / ps + b2[idx * 2 + 1];
  bool act = (c0 < 20);
  float mx = act ? fmaxf(v0, v1) : -INFINITY;
  #pragma unroll
  for (int o = 16; o; o >>= 1) mx = fmaxf(mx, __shfl_xor(mx, o, 64));
  float exs = act ? (__expf(v0 - mx) + __expf(v1 - mx)) : 0.f;
  #pragma unroll
  for (int o = 16; o; o >>= 1) exs += __shfl_xor(exs, o, 64);
  float lse = mx + logf(exs);
  if (lane < 20){
    float2 o2; o2.x = v0 - lse; o2.y = v1 - lse;
    *(float2*)(out + (size_t)d * 40 + lane * 2) = o2;
  }
}

extern "C" void kernel_launch(void* const* d_in, const int* in_sizes, int n_in,
                              void* d_out, int out_size, void* d_ws, size_t ws_size,
                              hipStream_t stream){
  const float* x   = (const float*)d_in[0];
  const int*   ei  = (const int*)d_in[1];
  const float* W1  = (const float*)d_in[2];
  const float* a1s = (const float*)d_in[3];
  const float* a1d = (const float*)d_in[4];
  const float* b1  = (const float*)d_in[5];
  const float* W2  = (const float*)d_in[6];
  const float* a2s = (const float*)d_in[7];
  const float* a2d = (const float*)d_in[8];
  const float* b2  = (const float*)d_in[9];
  float* out = (float*)d_out;

  const int N = in_sizes[0] / 256;
  const int E = in_sizes[1] / 2;
  const int tot = E + N;
  const int nb  = (N + 255) >> 8;

  float* ws = (float*)d_ws;
  size_t o = 0;
  float* as1  = ws + o; o += (size_t)N * 8;
  float* ad1  = ws + o; o += (size_t)N * 8;
  unsigned short* out1b = (unsigned short*)(ws + o); o += (size_t)N * 32;  // aliases `staged`
  unsigned short* h1b   = (unsigned short*)(ws + o); o += (size_t)N * 32;
  unsigned short* h2b   = (unsigned short*)(ws + o); o += (size_t)N * 20;
  unsigned* off_ = (unsigned*)(ws + o); o += (size_t)N;
  unsigned* cur  = (unsigned*)(ws + o); o += (size_t)N;
  int* srcids    = (int*)(ws + o);      o += (size_t)tot;
  short* wt_hi   = (short*)(ws + o);    o += 8192;   // 16384 bf16
  short* wt_lo   = (short*)(ws + o);    o += 8192;
  short* wt2_hi  = (short*)(ws + o);    o += 1536;   // 3072 bf16 (48x64)
  short* wt2_lo  = (short*)(ws + o);    o += 1536;
  unsigned* bcnt  = (unsigned*)(ws + o); o += nb;
  unsigned* bbase = (unsigned*)(ws + o); o += nb + 1;
  unsigned* bcur  = (unsigned*)(ws + o); o += nb;
  unsigned* staged = (unsigned*)out1b;
  float* as2 = as1;
  float* ad2 = ad1;

  const int cb = (tot + 8191) / 8192;

  hipMemsetAsync(bcnt, 0, sizeof(unsigned) * (size_t)nb, stream);

  // bucketed CSR build
  k_bincnt <<<cb, 256, 0, stream>>>(ei, E, N, nb, bcnt);
  k_bscan  <<<1, 512, 0, stream>>>(bcnt, bbase, bcur, nb, tot);
  k_binscat<<<cb, 256, 0, stream>>>(ei, E, N, nb, bcur, staged);
  k_csr    <<<nb, 256, 0, stream>>>(bbase, staged, N, off_, cur, srcids);

  // weight prep
  k_wprep <<<64, 256, 0, stream>>>(W1, wt_hi, wt_lo);
  k_w2prep<<<12, 256, 0, stream>>>(W2, wt2_hi, wt2_lo);

  // layer 1
  k_gemm1_mfma<<<(N + 63) / 64, 256, 0, stream>>>(x, wt_hi, wt_lo, a1s, a1d, h1b, as1, ad1, N);
  k_gat1 <<<(N + 3) / 4, 256, 0, stream>>>(off_, cur, srcids, as1, ad1, h1b, b1, out1b, N);

  // layer 2
  k_gemm2m<<<(N + 63) / 64, 256, 0, stream>>>(out1b, wt2_hi, wt2_lo, a2s, a2d, h2b, as2, ad2, N);
  k_gat2  <<<(N + 3) / 4, 256, 0, stream>>>(off_, cur, srcids, as2, ad2, h2b, b2, out, N);
}

// Round 13
// 261.209 us; speedup vs baseline: 1.0312x; 1.0312x over previous
//
#include <hip/hip_runtime.h>
#include <math.h>

#define NEG_SLOPE 0.2f
__device__ __forceinline__ float lrelu(float x){ return x >= 0.f ? x : NEG_SLOPE * x; }

typedef __attribute__((ext_vector_type(8))) short bf16x8;
typedef __attribute__((ext_vector_type(4))) float f32x4;

__device__ __forceinline__ float wred_sum(float v){
  #pragma unroll
  for (int o = 32; o; o >>= 1) v += __shfl_xor(v, o, 64);
  return v;
}

__device__ __forceinline__ float bfhi_f(float f){
  return __uint_as_float(__float_as_uint(f) & 0xFFFF0000u);
}
// fp32 -> bf16 RTNE
__device__ __forceinline__ unsigned short f2bf(float f){
  unsigned u = __float_as_uint(f);
  unsigned r = u + 0x7FFFu + ((u >> 16) & 1u);
  return (unsigned short)(r >> 16);
}

// ================= bucketed CSR build =================
__global__ __launch_bounds__(256) void k_bincnt(const int* __restrict__ ei, int E, int N, int nb,
                                                unsigned* __restrict__ bcnt){
  __shared__ unsigned h[512];
  const int tot = E + N;
  for (int i = threadIdx.x; i < nb; i += 256) h[i] = 0;
  __syncthreads();
  int base = blockIdx.x * 8192;
  #pragma unroll 4
  for (int j = 0; j < 32; j++){
    int e = base + threadIdx.x + j * 256;
    if (e < tot){
      unsigned d = (e < E) ? (unsigned)ei[E + e] : (unsigned)(e - E);
      atomicAdd(&h[d >> 8], 1u);
    }
  }
  __syncthreads();
  for (int i = threadIdx.x; i < nb; i += 256)
    if (h[i]) atomicAdd(&bcnt[i], h[i]);
}

__global__ void k_bscan(const unsigned* __restrict__ bcnt, unsigned* __restrict__ bbase,
                        unsigned* __restrict__ bcur, int nb, int tot){
  __shared__ unsigned s[512];
  int t = threadIdx.x;
  unsigned v = (t < nb) ? bcnt[t] : 0u;
  s[t] = v; __syncthreads();
  for (int off = 1; off < 512; off <<= 1){
    unsigned x = (t >= off) ? s[t - off] : 0u; __syncthreads();
    s[t] += x; __syncthreads();
  }
  if (t < nb){ unsigned b = s[t] - v; bbase[t] = b; bcur[t] = b; }
  if (t == 0) bbase[nb] = (unsigned)tot;
}

__global__ __launch_bounds__(256) void k_binscat(const int* __restrict__ ei, int E, int N, int nb,
    unsigned* __restrict__ bcur, unsigned* __restrict__ staged){
  __shared__ unsigned sd[8192];
  __shared__ unsigned hist[512];
  __shared__ unsigned runb[512];
  const int tot = E + N;
  for (int i = threadIdx.x; i < nb; i += 256) hist[i] = 0;
  __syncthreads();
  int base = blockIdx.x * 8192;
  #pragma unroll 4
  for (int j = 0; j < 32; j++){
    int idx = threadIdx.x + j * 256;
    int e = base + idx;
    unsigned d = 0xFFFFFFFFu;
    if (e < tot) d = (e < E) ? (unsigned)ei[E + e] : (unsigned)(e - E);
    sd[idx] = d;
    if (d != 0xFFFFFFFFu) atomicAdd(&hist[d >> 8], 1u);
  }
  __syncthreads();
  for (int i = threadIdx.x; i < nb; i += 256){
    unsigned c = hist[i];
    runb[i] = c ? atomicAdd(&bcur[i], c) : 0u;
    hist[i] = 0;
  }
  __syncthreads();
  #pragma unroll 4
  for (int j = 0; j < 32; j++){
    int idx = threadIdx.x + j * 256;
    unsigned d = sd[idx];
    if (d == 0xFFFFFFFFu) continue;
    int e = base + idx;
    unsigned s = (e < E) ? (unsigned)ei[e] : d;
    unsigned b = d >> 8;
    unsigned pos = runb[b] + atomicAdd(&hist[b], 1u);
    staged[pos] = s | ((d & 255u) << 20);
  }
}

__global__ __launch_bounds__(256) void k_csr(const unsigned* __restrict__ bbase,
    const unsigned* __restrict__ staged, int N,
    unsigned* __restrict__ off_, unsigned* __restrict__ cur, int* __restrict__ srcids){
  __shared__ unsigned cnt[256], scn[256], cnt2[256];
  int b = blockIdx.x, t = threadIdx.x;
  unsigned beg = bbase[b], end = bbase[b + 1];
  cnt[t] = 0; cnt2[t] = 0;
  __syncthreads();
  for (unsigned i = beg + t; i < end; i += 256)
    atomicAdd(&cnt[staged[i] >> 20], 1u);
  __syncthreads();
  unsigned v = cnt[t];
  scn[t] = v; __syncthreads();
  for (int off = 1; off < 256; off <<= 1){
    unsigned x = (t >= off) ? scn[t - off] : 0u; __syncthreads();
    scn[t] += x; __syncthreads();
  }
  unsigned ex = scn[t] - v;
  int d = b * 256 + t;
  if (d < N){ off_[d] = beg + ex; cur[d] = beg + ex + v; }
  cnt[t] = ex;
  __syncthreads();
  for (unsigned i = beg + t; i < end; i += 256){
    unsigned u = staged[i];
    unsigned dl = u >> 20;
    unsigned pos = beg + cnt[dl] + atomicAdd(&cnt2[dl], 1u);
    srcids[pos] = (int)(u & 0xFFFFFu);
  }
}

// ============ W1 prep: Wt_hi/Wt_lo[64][256] bf16 ============
__global__ void k_wprep(const float* __restrict__ W, short* __restrict__ wt_hi,
                        short* __restrict__ wt_lo){
  int i = blockIdx.x * 256 + threadIdx.x;    // 16384
  int k = i >> 6, c = i & 63;
  float v = W[i];
  unsigned u = __float_as_uint(v);
  wt_hi[c * 256 + k] = (short)(u >> 16);
  float lo = v - bfhi_f(v);
  wt_lo[c * 256 + k] = (short)(__float_as_uint(lo) >> 16);
}

// ============ W2 prep: [48][64] bf16 hi/lo (cols 40-47 zero) ============
__global__ void k_w2prep(const float* __restrict__ W2, short* __restrict__ hi,
                         short* __restrict__ lo){
  int i = blockIdx.x * 256 + threadIdx.x;    // 3072
  if (i >= 48 * 64) return;
  int c = i >> 6, k = i & 63;
  float v = (c < 40) ? W2[k * 40 + c] : 0.f;
  unsigned u = __float_as_uint(v);
  hi[c * 64 + k] = (short)(u >> 16);
  float l = v - bfhi_f(v);
  lo[c * 64 + k] = (short)(__float_as_uint(l) >> 16);
}

// ============ GEMM1 via MFMA: K-split across wave pairs for 2.7x TLP ============
// Block = 2 row-tiles x 2 K-halves (K=128 each). R8's proven low-VGPR inner loop;
// partials combined via padded LDS. Grid doubles -> ~32 resident waves/CU
// (gat1's 75%-occupancy regime, which sustains 2.5 TB/s on this memory system).
__global__ __launch_bounds__(256) void k_gemm1_mfma(const float* __restrict__ x,
    const short* __restrict__ wt_hi, const short* __restrict__ wt_lo,
    const float* __restrict__ a1s, const float* __restrict__ a1d,
    unsigned short* __restrict__ h1b, float* __restrict__ as_, float* __restrict__ ad_, int N){
  __shared__ float cacc[2][64][17];          // padded: lane stride 17 -> conflict-free
  int lane = threadIdx.x & 63;
  int wv   = threadIdx.x >> 6;
  int tile = wv >> 1;                        // 0..1 : row-tile within block
  int kh   = wv & 1;                         // 0..1 : K-half (128 each)
  int r0   = blockIdx.x * 32 + tile * 16;
  int col16 = lane & 15;
  int kg    = lane >> 4;
  const float* xr = x + (size_t)min(r0 + col16, N - 1) * 256 + kh * 128 + kg * 8;

  f32x4 acc[4];
  #pragma unroll
  for (int ct = 0; ct < 4; ct++) acc[ct] = (f32x4){0.f, 0.f, 0.f, 0.f};

  #pragma unroll 2
  for (int kt = 0; kt < 4; kt++){
    float4 v0 = *(const float4*)(xr + kt * 32);
    float4 v1 = *(const float4*)(xr + kt * 32 + 4);
    unsigned u[8] = {__float_as_uint(v0.x), __float_as_uint(v0.y), __float_as_uint(v0.z), __float_as_uint(v0.w),
                     __float_as_uint(v1.x), __float_as_uint(v1.y), __float_as_uint(v1.z), __float_as_uint(v1.w)};
    union { bf16x8 v; unsigned u[4]; } ahi, alo;
    #pragma unroll
    for (int j = 0; j < 4; j++)
      ahi.u[j] = __builtin_amdgcn_perm(u[2*j+1], u[2*j], 0x07060302);
    float lo[8];
    lo[0] = v0.x - bfhi_f(v0.x); lo[1] = v0.y - bfhi_f(v0.y);
    lo[2] = v0.z - bfhi_f(v0.z); lo[3] = v0.w - bfhi_f(v0.w);
    lo[4] = v1.x - bfhi_f(v1.x); lo[5] = v1.y - bfhi_f(v1.y);
    lo[6] = v1.z - bfhi_f(v1.z); lo[7] = v1.w - bfhi_f(v1.w);
    #pragma unroll
    for (int j = 0; j < 4; j++)
      alo.u[j] = __builtin_amdgcn_perm(__float_as_uint(lo[2*j+1]), __float_as_uint(lo[2*j]), 0x07060302);

    int ktg = kh * 4 + kt;                   // global K-step index
    #pragma unroll
    for (int ct = 0; ct < 4; ct++){
      int wcol = ct * 16 + col16;
      const bf16x8 bhi = *(const bf16x8*)(wt_hi + wcol * 256 + ktg * 32 + kg * 8);
      const bf16x8 blo = *(const bf16x8*)(wt_lo + wcol * 256 + ktg * 32 + kg * 8);
      acc[ct] = __builtin_amdgcn_mfma_f32_16x16x32_bf16(ahi.v, bhi, acc[ct], 0, 0, 0);
      acc[ct] = __builtin_amdgcn_mfma_f32_16x16x32_bf16(ahi.v, blo, acc[ct], 0, 0, 0);
      acc[ct] = __builtin_amdgcn_mfma_f32_16x16x32_bf16(alo.v, bhi, acc[ct], 0, 0, 0);
    }
  }

  // combine K-halves via LDS (kh=1 stores, kh=0 adds + epilogue)
  if (kh == 1){
    #pragma unroll
    for (int ct = 0; ct < 4; ct++)
      #pragma unroll
      for (int r = 0; r < 4; r++)
        cacc[tile][lane][ct * 4 + r] = acc[ct][r];
  }
  __syncthreads();
  if (kh == 1) return;

  #pragma unroll
  for (int ct = 0; ct < 4; ct++)
    #pragma unroll
    for (int r = 0; r < 4; r++)
      acc[ct][r] += cacc[tile][lane][ct * 4 + r];

  float cs[4], cd[4];
  #pragma unroll
  for (int ct = 0; ct < 4; ct++){ cs[ct] = a1s[ct * 16 + col16]; cd[ct] = a1d[ct * 16 + col16]; }
  #pragma unroll
  for (int r = 0; r < 4; r++){
    int rr = r0 + kg * 4 + r;
    bool ok = rr < N;
    #pragma unroll
    for (int ct = 0; ct < 4; ct++){
      float v = acc[ct][r];
      if (ok) h1b[(size_t)rr * 64 + ct * 16 + col16] = f2bf(v);
      float s = v * cs[ct];
      float t = v * cd[ct];
      s += __shfl_xor(s, 1, 64); s += __shfl_xor(s, 2, 64); s += __shfl_xor(s, 4, 64);
      t += __shfl_xor(t, 1, 64); t += __shfl_xor(t, 2, 64); t += __shfl_xor(t, 4, 64);
      if (ok && (col16 & 7) == 0){
        int head = ct * 2 + (col16 >> 3);
        as_[(size_t)rr * 8 + head] = s;
        ad_[(size_t)rr * 8 + head] = t;
      }
    }
  }
}

// ============ layer-1 per-dst gather: staged srcids, MLP-4 channel phase ============
__global__ __launch_bounds__(256) void k_gat1(const unsigned* __restrict__ off_, const unsigned* __restrict__ cur,
    const int* __restrict__ srcids, const float* __restrict__ as_, const float* __restrict__ ad_,
    const unsigned short* __restrict__ h1b, const float* __restrict__ b1,
    unsigned short* __restrict__ out1b, int N){
  int lane = threadIdx.x & 63;
  int wv   = threadIdx.x >> 6;
  int d    = blockIdx.x * 4 + wv;
  if (d >= N) return;
  __shared__ float lds_p[4][64 * 8];
  __shared__ int   lds_s[4][64];
  float* lp = lds_p[wv];
  int*   ls = lds_s[wv];
  unsigned beg = off_[d], fin = cur[d];

  int e8 = lane >> 3, h = lane & 7;                  // exp-phase layout
  int c0 = lane & 31, pe = lane >> 5, hh = c0 >> 2;  // channel-phase layout
  float adh = ad_[(size_t)d * 8 + h];
  float psacc = 0.f, accx = 0.f, accy = 0.f;

  for (unsigned base = beg; base < fin; base += 64){
    int nthis = (int)min(64u, fin - base);
    unsigned i = base + lane;
    ls[lane] = (i < fin) ? srcids[i] : 0;            // one coalesced stage
    asm volatile("s_waitcnt lgkmcnt(0)" ::: "memory");
    __builtin_amdgcn_sched_barrier(0);
    for (int j = 0; j < nthis; j += 8){
      int eloc = j + e8;
      int s = ls[eloc];
      float p = 0.f;
      if (eloc < nthis) p = __expf(lrelu(as_[(size_t)s * 8 + h] + adh));
      lp[eloc * 8 + h] = p;
      psacc += p;
    }
    asm volatile("s_waitcnt lgkmcnt(0)" ::: "memory");
    __builtin_amdgcn_sched_barrier(0);
    for (int e = 0; e < nthis; e += 8){
      int e0 = e + pe, e1 = e + 2 + pe, e2 = e + 4 + pe, e3 = e + 6 + pe;
      float p0 = lp[e0 * 8 + hh], p1 = lp[e1 * 8 + hh];
      float p2 = lp[e2 * 8 + hh], p3 = lp[e3 * 8 + hh];
      int s0 = ls[e0], s1 = ls[e1], s2 = ls[e2], s3 = ls[e3];
      unsigned u0 = *(const unsigned*)(h1b + (size_t)s0 * 64 + c0 * 2);
      unsigned u1 = *(const unsigned*)(h1b + (size_t)s1 * 64 + c0 * 2);
      unsigned u2 = *(const unsigned*)(h1b + (size_t)s2 * 64 + c0 * 2);
      unsigned u3 = *(const unsigned*)(h1b + (size_t)s3 * 64 + c0 * 2);
      accx = fmaf(p0, __uint_as_float(u0 << 16), accx);
      accy = fmaf(p0, __uint_as_float(u0 & 0xFFFF0000u), accy);
      accx = fmaf(p1, __uint_as_float(u1 << 16), accx);
      accy = fmaf(p1, __uint_as_float(u1 & 0xFFFF0000u), accy);
      accx = fmaf(p2, __uint_as_float(u2 << 16), accx);
      accy = fmaf(p2, __uint_as_float(u2 & 0xFFFF0000u), accy);
      accx = fmaf(p3, __uint_as_float(u3 << 16), accx);
      accy = fmaf(p3, __uint_as_float(u3 & 0xFFFF0000u), accy);
    }
    asm volatile("" ::: "memory");
  }
  float den = psacc;
  den += __shfl_xor(den, 8, 64);
  den += __shfl_xor(den, 16, 64);
  den += __shfl_xor(den, 32, 64);
  float mydenv = __shfl(den, hh, 64);
  accx += __shfl_xor(accx, 32, 64);
  accy += __shfl_xor(accy, 32, 64);
  if (lane < 32){
    int ch = lane * 2;
    float v0 = accx / mydenv + b1[ch];
    float v1 = accy / mydenv + b1[ch + 1];
    ushort2 o;
    o.x = f2bf(v0 > 0.f ? v0 : 0.f);
    o.y = f2bf(v1 > 0.f ? v1 : 0.f);
    *(ushort2*)(out1b + (size_t)d * 64 + ch) = o;
  }
}

// ============ GEMM2 via MFMA (bf16 A, hi/lo B) + fused alpha2 ============
__global__ __launch_bounds__(256) void k_gemm2m(const unsigned short* __restrict__ out1b,
    const short* __restrict__ wt2_hi, const short* __restrict__ wt2_lo,
    const float* __restrict__ a2s, const float* __restrict__ a2d,
    unsigned short* __restrict__ h2b, float* __restrict__ as_, float* __restrict__ ad_, int N){
  int lane = threadIdx.x & 63;
  int wv   = threadIdx.x >> 6;
  int r0   = blockIdx.x * 64 + wv * 16;
  if (r0 >= N) return;
  int col16 = lane & 15;
  int kg    = lane >> 4;
  const unsigned short* ar = out1b + (size_t)min(r0 + col16, N - 1) * 64 + kg * 8;

  f32x4 acc[3];
  #pragma unroll
  for (int ct = 0; ct < 3; ct++) acc[ct] = (f32x4){0.f, 0.f, 0.f, 0.f};

  #pragma unroll
  for (int kt = 0; kt < 2; kt++){
    const bf16x8 a = *(const bf16x8*)(ar + kt * 32);
    #pragma unroll
    for (int ct = 0; ct < 3; ct++){
      int wcol = ct * 16 + col16;
      const bf16x8 bhi = *(const bf16x8*)(wt2_hi + wcol * 64 + kt * 32 + kg * 8);
      const bf16x8 blo = *(const bf16x8*)(wt2_lo + wcol * 64 + kt * 32 + kg * 8);
      acc[ct] = __builtin_amdgcn_mfma_f32_16x16x32_bf16(a, bhi, acc[ct], 0, 0, 0);
      acc[ct] = __builtin_amdgcn_mfma_f32_16x16x32_bf16(a, blo, acc[ct], 0, 0, 0);
    }
  }

  float cs[3], cd[3];
  #pragma unroll
  for (int ct = 0; ct < 3; ct++){
    int col = ct * 16 + col16;
    bool okc = col < 40;
    cs[ct] = okc ? a2s[col] : 0.f;
    cd[ct] = okc ? a2d[col] : 0.f;
  }
  #pragma unroll
  for (int r = 0; r < 4; r++){
    int rr = r0 + kg * 4 + r;
    bool ok = rr < N;
    float s = 0.f, t = 0.f;
    #pragma unroll
    for (int ct = 0; ct < 3; ct++){
      s = fmaf(acc[ct][r], cs[ct], s);
      t = fmaf(acc[ct][r], cd[ct], t);
      int col = ct * 16 + col16;
      if (ok && col < 40) h2b[(size_t)rr * 40 + col] = f2bf(acc[ct][r]);
    }
    s += __shfl_xor(s, 1, 64); s += __shfl_xor(s, 2, 64);
    s += __shfl_xor(s, 4, 64); s += __shfl_xor(s, 8, 64);
    t += __shfl_xor(t, 1, 64); t += __shfl_xor(t, 2, 64);
    t += __shfl_xor(t, 4, 64); t += __shfl_xor(t, 8, 64);
    if (ok && col16 == 0){ as_[rr] = s; ad_[rr] = t; }
  }
}

// ============ layer-2 per-dst gather (H=1, C=40), MLP-4 + fused bias+log_softmax ============
__global__ __launch_bounds__(256) void k_gat2(const unsigned* __restrict__ off_, const unsigned* __restrict__ cur,
    const int* __restrict__ srcids, const float* __restrict__ as_, const float* __restrict__ ad_,
    const unsigned short* __restrict__ h2b, const float* __restrict__ b2, float* __restrict__ out, int N){
  int lane = threadIdx.x & 63;
  int wv   = threadIdx.x >> 6;
  int d    = blockIdx.x * 4 + wv;
  if (d >= N) return;
  __shared__ float lds_p[4][64];
  __shared__ int   lds_s[4][64];
  float* lp = lds_p[wv];
  int*   ls = lds_s[wv];
  unsigned beg = off_[d], fin = cur[d];
  float add = ad_[d];

  int c0 = lane & 31;
  int pe = lane >> 5;
  int idx = c0 < 20 ? c0 : 19;
  float ps = 0.f, accx = 0.f, accy = 0.f;

  for (unsigned base = beg; base < fin; base += 64){
    unsigned i = base + lane;
    int nthis = (int)min(64u, fin - base);
    if (i < fin){
      int s = srcids[i];
      float p = __expf(lrelu(as_[s] + add));
      ps += p; ls[lane] = s; lp[lane] = p;
    } else { ls[lane] = 0; lp[lane] = 0.f; }
    asm volatile("s_waitcnt lgkmcnt(0)" ::: "memory");
    __builtin_amdgcn_sched_barrier(0);
    for (int e = 0; e < nthis; e += 8){
      int e0 = e + pe, e1 = e + 2 + pe, e2 = e + 4 + pe, e3 = e + 6 + pe;
      float p0 = lp[e0], p1 = lp[e1], p2 = lp[e2], p3 = lp[e3];
      int s0 = ls[e0], s1 = ls[e1], s2 = ls[e2], s3 = ls[e3];
      unsigned u0 = *(const unsigned*)(h2b + (size_t)s0 * 40 + idx * 2);
      unsigned u1 = *(const unsigned*)(h2b + (size_t)s1 * 40 + idx * 2);
      unsigned u2 = *(const unsigned*)(h2b + (size_t)s2 * 40 + idx * 2);
      unsigned u3 = *(const unsigned*)(h2b + (size_t)s3 * 40 + idx * 2);
      accx = fmaf(p0, __uint_as_float(u0 << 16), accx);
      accy = fmaf(p0, __uint_as_float(u0 & 0xFFFF0000u), accy);
      accx = fmaf(p1, __uint_as_float(u1 << 16), accx);
      accy = fmaf(p1, __uint_as_float(u1 & 0xFFFF0000u), accy);
      accx = fmaf(p2, __uint_as_float(u2 << 16), accx);
      accy = fmaf(p2, __uint_as_float(u2 & 0xFFFF0000u), accy);
      accx = fmaf(p3, __uint_as_float(u3 << 16), accx);
      accy = fmaf(p3, __uint_as_float(u3 & 0xFFFF0000u), accy);
    }
    asm volatile("" ::: "memory");
  }
  ps = wred_sum(ps);
  accx += __shfl_xor(accx, 32, 64);
  accy += __shfl_xor(accy, 32, 64);

  float v0 = accx / ps + b2[idx * 2];
  float v1 = accy / ps + b2[idx * 2 + 1];
  bool act = (c0 < 20);
  float mx = act ? fmaxf(v0, v1) : -INFINITY;
  #pragma unroll
  for (int o = 16; o; o >>= 1) mx = fmaxf(mx, __shfl_xor(mx, o, 64));
  float exs = act ? (__expf(v0 - mx) + __expf(v1 - mx)) : 0.f;
  #pragma unroll
  for (int o = 16; o; o >>= 1) exs += __shfl_xor(exs, o, 64);
  float lse = mx + logf(exs);
  if (lane < 20){
    float2 o2; o2.x = v0 - lse; o2.y = v1 - lse;
    *(float2*)(out + (size_t)d * 40 + lane * 2) = o2;
  }
}

extern "C" void kernel_launch(void* const* d_in, const int* in_sizes, int n_in,
                              void* d_out, int out_size, void* d_ws, size_t ws_size,
                              hipStream_t stream){
  const float* x   = (const float*)d_in[0];
  const int*   ei  = (const int*)d_in[1];
  const float* W1  = (const float*)d_in[2];
  const float* a1s = (const float*)d_in[3];
  const float* a1d = (const float*)d_in[4];
  const float* b1  = (const float*)d_in[5];
  const float* W2  = (const float*)d_in[6];
  const float* a2s = (const float*)d_in[7];
  const float* a2d = (const float*)d_in[8];
  const float* b2  = (const float*)d_in[9];
  float* out = (float*)d_out;

  const int N = in_sizes[0] / 256;
  const int E = in_sizes[1] / 2;
  const int tot = E + N;
  const int nb  = (N + 255) >> 8;

  float* ws = (float*)d_ws;
  size_t o = 0;
  float* as1  = ws + o; o += (size_t)N * 8;
  float* ad1  = ws + o; o += (size_t)N * 8;
  unsigned short* out1b = (unsigned short*)(ws + o); o += (size_t)N * 32;  // aliases `staged`
  unsigned short* h1b   = (unsigned short*)(ws + o); o += (size_t)N * 32;
  unsigned short* h2b   = (unsigned short*)(ws + o); o += (size_t)N * 20;
  unsigned* off_ = (unsigned*)(ws + o); o += (size_t)N;
  unsigned* cur  = (unsigned*)(ws + o); o += (size_t)N;
  int* srcids    = (int*)(ws + o);      o += (size_t)tot;
  short* wt_hi   = (short*)(ws + o);    o += 8192;   // 16384 bf16
  short* wt_lo   = (short*)(ws + o);    o += 8192;
  short* wt2_hi  = (short*)(ws + o);    o += 1536;   // 3072 bf16 (48x64)
  short* wt2_lo  = (short*)(ws + o);    o += 1536;
  unsigned* bcnt  = (unsigned*)(ws + o); o += nb;
  unsigned* bbase = (unsigned*)(ws + o); o += nb + 1;
  unsigned* bcur  = (unsigned*)(ws + o); o += nb;
  unsigned* staged = (unsigned*)out1b;
  float* as2 = as1;
  float* ad2 = ad1;

  const int cb = (tot + 8191) / 8192;

  hipMemsetAsync(bcnt, 0, sizeof(unsigned) * (size_t)nb, stream);

  // bucketed CSR build
  k_bincnt <<<cb, 256, 0, stream>>>(ei, E, N, nb, bcnt);
  k_bscan  <<<1, 512, 0, stream>>>(bcnt, bbase, bcur, nb, tot);
  k_binscat<<<cb, 256, 0, stream>>>(ei, E, N, nb, bcur, staged);
  k_csr    <<<nb, 256, 0, stream>>>(bbase, staged, N, off_, cur, srcids);

  // weight prep
  k_wprep <<<64, 256, 0, stream>>>(W1, wt_hi, wt_lo);
  k_w2prep<<<12, 256, 0, stream>>>(W2, wt2_hi, wt2_lo);

  // layer 1
  k_gemm1_mfma<<<(N + 31) / 32, 256, 0, stream>>>(x, wt_hi, wt_lo, a1s, a1d, h1b, as1, ad1, N);
  k_gat1 <<<(N + 3) / 4, 256, 0, stream>>>(off_, cur, srcids, as1, ad1, h1b, b1, out1b, N);

  // layer 2
  k_gemm2m<<<(N + 63) / 64, 256, 0, stream>>>(out1b, wt2_hi, wt2_lo, a2s, a2d, h2b, as2, ad2, N);
  k_gat2  <<<(N + 3) / 4, 256, 0, stream>>>(off_, cur, srcids, as2, ad2, h2b, b2, out, N);
}